// Round 1
// baseline (2676.122 us; speedup 1.0000x reference)
//
#include <hip/hip_runtime.h>
#include <hip/hip_bf16.h>

// Problem: B=4, T=2048, D=768, H=12, DH=64, causal MHA + QKV/out projections.
// All inputs fp32; internals bf16 (threshold 8*bf16eps permits this).

#define BATCH  4
#define SEQ    2048
#define DMODEL 768
#define NH     12
#define DHEAD  64
// SCALE = 1/sqrt(64) = 0.125 ; folded with log2(e) for base-2 softmax
static constexpr float SCALE_LOG2E = 0.125f * 1.4426950408889634f;

typedef __bf16 v8bf __attribute__((ext_vector_type(8)));
typedef float  v4f  __attribute__((ext_vector_type(4)));

__device__ __forceinline__ float bfbits2f(unsigned short u) {
    return __builtin_bit_cast(float, (unsigned int)(((unsigned int)u) << 16));
}

// load 8 fp32, round to bf16 fragment (A/B operand: 8 contiguous k per lane)
__device__ __forceinline__ v8bf cvt8(const float* __restrict__ p) {
    const float4 a = ((const float4*)p)[0];
    const float4 b = ((const float4*)p)[1];
    v8bf r;
    r[0] = (__bf16)a.x; r[1] = (__bf16)a.y; r[2] = (__bf16)a.z; r[3] = (__bf16)a.w;
    r[4] = (__bf16)b.x; r[5] = (__bf16)b.y; r[6] = (__bf16)b.z; r[7] = (__bf16)b.w;
    return r;
}

// ---------------------------------------------------------------------------
// Kernel 1: qkv = x @ Wqkv^T  (M=8192, N=2304, K=768), scatter to Q/K/V
// [B*H, T, DH] bf16. Block=256 (4 waves), block tile 64x128, wave tile 32x64.
// MFMA layouts (HW-verified): A[m=lane&15][k=quad*8+j]; B^T rows load same way;
// C/D: col=lane&15, row=quad*4+reg.
// ---------------------------------------------------------------------------
__global__ __launch_bounds__(256) void qkv_kernel(
        const float* __restrict__ x, const float* __restrict__ Wqkv,
        __bf16* __restrict__ Qb, __bf16* __restrict__ Kb, __bf16* __restrict__ Vb) {
    const int lane = threadIdx.x & 63;
    const int wave = threadIdx.x >> 6;
    const int nb = blockIdx.x % 18;   // 2304/128
    const int mb = blockIdx.x / 18;   // 8192/64
    const int waveM = mb * 64 + (wave >> 1) * 32;
    const int waveN = nb * 128 + (wave & 1) * 64;
    const int r16 = lane & 15;
    const int quad = lane >> 4;

    v4f acc[2][4] = {};
    for (int k0 = 0; k0 < DMODEL; k0 += 32) {
        const int kq = k0 + quad * 8;
        v8bf af[2], bfr[4];
#pragma unroll
        for (int i = 0; i < 2; ++i)
            af[i] = cvt8(x + (size_t)(waveM + i * 16 + r16) * DMODEL + kq);
#pragma unroll
        for (int j = 0; j < 4; ++j)
            bfr[j] = cvt8(Wqkv + (size_t)(waveN + j * 16 + r16) * DMODEL + kq);
#pragma unroll
        for (int i = 0; i < 2; ++i)
#pragma unroll
            for (int j = 0; j < 4; ++j)
                acc[i][j] = __builtin_amdgcn_mfma_f32_16x16x32_bf16(
                    af[i], bfr[j], acc[i][j], 0, 0, 0);
    }

#pragma unroll
    for (int j = 0; j < 4; ++j) {
        const int nbase = waveN + j * 16;        // 16-col subtile within one of Q/K/V
        const int seg = nbase / DMODEL;          // wave-uniform
        const int dm = nbase - seg * DMODEL + r16;
        const int h = dm >> 6;
        const int d = dm & 63;
        __bf16* dst = (seg == 0) ? Qb : (seg == 1 ? Kb : Vb);
#pragma unroll
        for (int i = 0; i < 2; ++i) {
#pragma unroll
            for (int r = 0; r < 4; ++r) {
                const int m = waveM + i * 16 + quad * 4 + r;
                const int b = m >> 11;           // /SEQ
                const int t = m & (SEQ - 1);
                dst[(((size_t)(b * NH + h)) * SEQ + t) * DHEAD + d] = (__bf16)acc[i][j][r];
            }
        }
    }
}

// ---------------------------------------------------------------------------
// Kernel 2: causal flash attention, one wave per (b,h,t) query row.
// Vector ALU, fp32 accumulation, base-2 online softmax.
// ---------------------------------------------------------------------------
__global__ __launch_bounds__(256) void attn_kernel(
        const __bf16* __restrict__ Qb, const __bf16* __restrict__ Kb,
        const __bf16* __restrict__ Vb, __bf16* __restrict__ attnb) {
    __shared__ float smem[4 * 128];
    const int lane = threadIdx.x & 63;
    const int wave = threadIdx.x >> 6;
    const int wid = blockIdx.x * 4 + wave;
    const int t  = wid & (SEQ - 1);
    const int bh = wid >> 11;                    // [0, 48)
    float* qs = smem + wave * 128;
    float* ps = qs + 64;

    const size_t base = (size_t)bh * SEQ * DHEAD;
    qs[lane] = (float)Qb[base + (size_t)t * DHEAD + lane] * SCALE_LOG2E;
    __builtin_amdgcn_s_waitcnt(0);               // wave-internal LDS RAW

    const unsigned short* Ku = (const unsigned short*)Kb + base;
    const unsigned short* Vu = (const unsigned short*)Vb + base;

    float o = 0.f, mrun = -1e30f, lrun = 0.f;
    for (int k0 = 0; k0 <= t; k0 += 64) {
        const int kk = k0 + lane;                // always < SEQ
        const unsigned short* Krow = Ku + (size_t)kk * DHEAD;
        float s = 0.f;
#pragma unroll
        for (int j = 0; j < 64; j += 4) {
            const float4 qv = *(const float4*)(qs + j);
            const ushort4 kv = *(const ushort4*)(Krow + j);
            s += qv.x * bfbits2f(kv.x) + qv.y * bfbits2f(kv.y)
               + qv.z * bfbits2f(kv.z) + qv.w * bfbits2f(kv.w);
        }
        if (kk > t) s = -1e30f;                  // causal mask

        float cm = s;
#pragma unroll
        for (int off = 32; off >= 1; off >>= 1)
            cm = fmaxf(cm, __shfl_xor(cm, off));
        const float mnew  = fmaxf(mrun, cm);
        const float p     = __builtin_exp2f(s - mnew);     // 0 for masked lanes
        const float alpha = __builtin_exp2f(mrun - mnew);
        float psum = p;
#pragma unroll
        for (int off = 32; off >= 1; off >>= 1)
            psum += __shfl_xor(psum, off);
        lrun = lrun * alpha + psum;
        o *= alpha;
        mrun = mnew;

        ps[lane] = p;
        __builtin_amdgcn_s_waitcnt(0);           // wave-internal LDS RAW
#pragma unroll
        for (int j = 0; j < 64; j += 4) {
            const float4 pv = *(const float4*)(ps + j);
            const unsigned short* Vrow = Vu + (size_t)(k0 + j) * DHEAD + lane;
            o += pv.x * bfbits2f(Vrow[0]);
            o += pv.y * bfbits2f(Vrow[DHEAD]);
            o += pv.z * bfbits2f(Vrow[2 * DHEAD]);
            o += pv.w * bfbits2f(Vrow[3 * DHEAD]);
        }
    }

    const int b = bh / NH, h = bh - b * NH;
    attnb[((size_t)(b * SEQ + t)) * DMODEL + h * DHEAD + lane] = (__bf16)(o / lrun);
}

// ---------------------------------------------------------------------------
// Kernel 3: out = attn @ Wproj^T + bproj  (M=8192, N=768, K=768), fp32 out.
// ---------------------------------------------------------------------------
__global__ __launch_bounds__(256) void proj_kernel(
        const __bf16* __restrict__ A, const float* __restrict__ Wp,
        const float* __restrict__ bias, float* __restrict__ out) {
    const int lane = threadIdx.x & 63;
    const int wave = threadIdx.x >> 6;
    const int nb = blockIdx.x % 6;    // 768/128
    const int mb = blockIdx.x / 6;    // 8192/64
    const int waveM = mb * 64 + (wave >> 1) * 32;
    const int waveN = nb * 128 + (wave & 1) * 64;
    const int r16 = lane & 15;
    const int quad = lane >> 4;

    v4f acc[2][4] = {};
    for (int k0 = 0; k0 < DMODEL; k0 += 32) {
        const int kq = k0 + quad * 8;
        v8bf af[2], bfr[4];
#pragma unroll
        for (int i = 0; i < 2; ++i)
            af[i] = *(const v8bf*)(A + (size_t)(waveM + i * 16 + r16) * DMODEL + kq);
#pragma unroll
        for (int j = 0; j < 4; ++j)
            bfr[j] = cvt8(Wp + (size_t)(waveN + j * 16 + r16) * DMODEL + kq);
#pragma unroll
        for (int i = 0; i < 2; ++i)
#pragma unroll
            for (int j = 0; j < 4; ++j)
                acc[i][j] = __builtin_amdgcn_mfma_f32_16x16x32_bf16(
                    af[i], bfr[j], acc[i][j], 0, 0, 0);
    }

#pragma unroll
    for (int j = 0; j < 4; ++j) {
        const int n = waveN + j * 16 + r16;
        const float bv = bias[n];
#pragma unroll
        for (int i = 0; i < 2; ++i) {
#pragma unroll
            for (int r = 0; r < 4; ++r) {
                const int m = waveM + i * 16 + quad * 4 + r;
                out[(size_t)m * DMODEL + n] = acc[i][j][r] + bv;
            }
        }
    }
}

// ---------------------------------------------------------------------------
extern "C" void kernel_launch(void* const* d_in, const int* in_sizes, int n_in,
                              void* d_out, int out_size, void* d_ws, size_t ws_size,
                              hipStream_t stream) {
    const float* x     = (const float*)d_in[0];
    const float* Wqkv  = (const float*)d_in[1];
    const float* Wproj = (const float*)d_in[2];
    const float* bproj = (const float*)d_in[3];
    float* out = (float*)d_out;

    char* ws = (char*)d_ws;
    const size_t tsz = (size_t)BATCH * NH * SEQ * DHEAD * sizeof(__bf16); // 12.58 MB
    __bf16* Qb    = (__bf16*)(ws);
    __bf16* Kb    = (__bf16*)(ws + tsz);
    __bf16* Vb    = (__bf16*)(ws + 2 * tsz);
    __bf16* attnb = (__bf16*)(ws + 3 * tsz);   // [B, T, D] bf16

    qkv_kernel<<<dim3(128 * 18), dim3(256), 0, stream>>>(x, Wqkv, Qb, Kb, Vb);
    attn_kernel<<<dim3(BATCH * NH * SEQ / 4), dim3(256), 0, stream>>>(Qb, Kb, Vb, attnb);
    proj_kernel<<<dim3(128 * 6), dim3(256), 0, stream>>>(attnb, Wproj, bproj, out);
}

// Round 2
// 595.698 us; speedup vs baseline: 4.4924x; 4.4924x over previous
//
#include <hip/hip_runtime.h>
#include <hip/hip_bf16.h>

// B=4, T=2048, D=768, H=12, DH=64, causal MHA + QKV/out projections.
// All inputs fp32; internals bf16 (threshold 8*bf16eps permits this).
//
// R2: MFMA flash attention. Q stored pre-scaled by SCALE*log2e (base-2
// softmax); V stored transposed [B,H,DH,T] so PV B-fragments are direct
// contiguous-key loads; P does the C->A layout round-trip through LDS.

#define BATCH  4
#define SEQ    2048
#define DMODEL 768
#define NH     12
#define DHEAD  64
static constexpr float SCALE_LOG2E = 0.125f * 1.4426950408889634f;

typedef __bf16 v8bf __attribute__((ext_vector_type(8)));
typedef float  v4f  __attribute__((ext_vector_type(4)));

__device__ __forceinline__ v8bf cvt8(const float* __restrict__ p) {
    const float4 a = ((const float4*)p)[0];
    const float4 b = ((const float4*)p)[1];
    v8bf r;
    r[0] = (__bf16)a.x; r[1] = (__bf16)a.y; r[2] = (__bf16)a.z; r[3] = (__bf16)a.w;
    r[4] = (__bf16)b.x; r[5] = (__bf16)b.y; r[6] = (__bf16)b.z; r[7] = (__bf16)b.w;
    return r;
}

// ---------------------------------------------------------------------------
// Kernel 1: qkv = x @ Wqkv^T (M=8192, N=2304, K=768).
// Q scatter: [B,H,T,64] bf16, pre-scaled by SCALE*log2e.
// K scatter: [B,H,T,64] bf16.
// V scatter: [B,H,64,T] bf16 (TRANSPOSED for PV B-fragments).
// ---------------------------------------------------------------------------
__global__ __launch_bounds__(256) void qkv_kernel(
        const float* __restrict__ x, const float* __restrict__ Wqkv,
        __bf16* __restrict__ Qb, __bf16* __restrict__ Kb, __bf16* __restrict__ Vtb) {
    const int lane = threadIdx.x & 63;
    const int wave = threadIdx.x >> 6;
    const int nb = blockIdx.x % 18;   // 2304/128
    const int mb = blockIdx.x / 18;   // 8192/64
    const int waveM = mb * 64 + (wave >> 1) * 32;
    const int waveN = nb * 128 + (wave & 1) * 64;
    const int r16 = lane & 15;
    const int quad = lane >> 4;

    v4f acc[2][4] = {};
    for (int k0 = 0; k0 < DMODEL; k0 += 32) {
        const int kq = k0 + quad * 8;
        v8bf af[2], bfr[4];
#pragma unroll
        for (int i = 0; i < 2; ++i)
            af[i] = cvt8(x + (size_t)(waveM + i * 16 + r16) * DMODEL + kq);
#pragma unroll
        for (int j = 0; j < 4; ++j)
            bfr[j] = cvt8(Wqkv + (size_t)(waveN + j * 16 + r16) * DMODEL + kq);
#pragma unroll
        for (int i = 0; i < 2; ++i)
#pragma unroll
            for (int j = 0; j < 4; ++j)
                acc[i][j] = __builtin_amdgcn_mfma_f32_16x16x32_bf16(
                    af[i], bfr[j], acc[i][j], 0, 0, 0);
    }

#pragma unroll
    for (int j = 0; j < 4; ++j) {
        const int nbase = waveN + j * 16;        // which 16-col subtile of [Q|K|V]
        const int seg = nbase / DMODEL;          // wave-uniform: 0=Q 1=K 2=V
        const int dm = nbase - seg * DMODEL + r16;
        const int h = dm >> 6;
        const int d = dm & 63;
        const float scl = (seg == 0) ? SCALE_LOG2E : 1.0f;
#pragma unroll
        for (int i = 0; i < 2; ++i) {
#pragma unroll
            for (int r = 0; r < 4; ++r) {
                const int m = waveM + i * 16 + quad * 4 + r;
                const int b = m >> 11;           // /SEQ
                const int t = m & (SEQ - 1);
                const size_t base = ((size_t)(b * NH + h)) * SEQ * DHEAD;
                const __bf16 val = (__bf16)(acc[i][j][r] * scl);
                if (seg == 0)      Qb[base + (size_t)t * DHEAD + d] = val;
                else if (seg == 1) Kb[base + (size_t)t * DHEAD + d] = val;
                else               Vtb[base + (size_t)d * SEQ + t] = val;
            }
        }
    }
}

// ---------------------------------------------------------------------------
// Kernel 2: MFMA causal flash attention.
// Block = 4 waves; wave owns 32 q-rows (block tile = 128 q); K-chunks of 64.
// Per chunk/wave: 16 QK MFMAs + online softmax (C-layout, shfl row stats)
// + P C->A round-trip via per-wave LDS + 16 PV MFMAs (V^T direct global).
// ---------------------------------------------------------------------------
__global__ __launch_bounds__(256) void attn_kernel(
        const __bf16* __restrict__ Qb, const __bf16* __restrict__ Kb,
        const __bf16* __restrict__ Vtb, __bf16* __restrict__ attnb) {
    __shared__ __align__(16) __bf16 Pl[4][32][72];  // per-wave P tile, padded
    const int lane = threadIdx.x & 63;
    const int wave = threadIdx.x >> 6;
    const int bh = blockIdx.x % (BATCH * NH);
    const int qt = 15 - (blockIdx.x / (BATCH * NH));  // longest blocks first
    const int q0 = qt * 128 + wave * 32;
    const int r16 = lane & 15;
    const int quad = lane >> 4;

    const __bf16* Q  = Qb  + (size_t)bh * SEQ * DHEAD;
    const __bf16* K  = Kb  + (size_t)bh * SEQ * DHEAD;
    const __bf16* Vt = Vtb + (size_t)bh * DHEAD * SEQ;

    // Q A-fragments: rows q0+16i+r16, k = kk*32 + quad*8 .. +7
    v8bf aq[2][2];
#pragma unroll
    for (int i = 0; i < 2; ++i)
#pragma unroll
        for (int kk = 0; kk < 2; ++kk)
            aq[i][kk] = *(const v8bf*)(Q + (size_t)(q0 + 16 * i + r16) * DHEAD
                                         + kk * 32 + quad * 8);

    v4f  oacc[2][4] = {};
    float mrun[2][4], lrun[2][4];
#pragma unroll
    for (int i = 0; i < 2; ++i)
#pragma unroll
        for (int r = 0; r < 4; ++r) { mrun[i][r] = -1e30f; lrun[i][r] = 0.f; }

    const int tmax = q0 + 31;
    for (int k0 = 0; k0 <= tmax; k0 += 64) {
        // ---- QK^T ----
        v8bf bk[4][2];
#pragma unroll
        for (int s = 0; s < 4; ++s)
#pragma unroll
            for (int kk = 0; kk < 2; ++kk)
                bk[s][kk] = *(const v8bf*)(K + (size_t)(k0 + 16 * s + r16) * DHEAD
                                             + kk * 32 + quad * 8);
        v4f sc[2][4] = {};
#pragma unroll
        for (int kk = 0; kk < 2; ++kk)
#pragma unroll
            for (int i = 0; i < 2; ++i)
#pragma unroll
                for (int s = 0; s < 4; ++s)
                    sc[i][s] = __builtin_amdgcn_mfma_f32_16x16x32_bf16(
                        aq[i][kk], bk[s][kk], sc[i][s], 0, 0, 0);

        // ---- causal mask (only chunks overlapping the diagonal) ----
        if (k0 + 63 > q0) {
#pragma unroll
            for (int i = 0; i < 2; ++i)
#pragma unroll
                for (int s = 0; s < 4; ++s)
#pragma unroll
                    for (int r = 0; r < 4; ++r) {
                        const int row = q0 + 16 * i + quad * 4 + r;
                        const int col = k0 + 16 * s + r16;
                        if (col > row) sc[i][s][r] = -1e30f;
                    }
        }

        // ---- online softmax (base-2; scale folded into Q) ----
        float rmax[2][4];
#pragma unroll
        for (int i = 0; i < 2; ++i)
#pragma unroll
            for (int r = 0; r < 4; ++r) {
                float m = fmaxf(fmaxf(sc[i][0][r], sc[i][1][r]),
                                fmaxf(sc[i][2][r], sc[i][3][r]));
#pragma unroll
                for (int off = 8; off >= 1; off >>= 1)
                    m = fmaxf(m, __shfl_xor(m, off));
                rmax[i][r] = m;
            }
        float alpha[2][4];
#pragma unroll
        for (int i = 0; i < 2; ++i)
#pragma unroll
            for (int r = 0; r < 4; ++r) {
                const float mnew = fmaxf(mrun[i][r], rmax[i][r]);
                alpha[i][r] = __builtin_exp2f(mrun[i][r] - mnew);
                mrun[i][r] = mnew;
            }
#pragma unroll
        for (int i = 0; i < 2; ++i)
#pragma unroll
            for (int s = 0; s < 4; ++s)
#pragma unroll
                for (int r = 0; r < 4; ++r)
                    sc[i][s][r] = __builtin_exp2f(sc[i][s][r] - mrun[i][r]);
#pragma unroll
        for (int i = 0; i < 2; ++i)
#pragma unroll
            for (int r = 0; r < 4; ++r) {
                float sum = sc[i][0][r] + sc[i][1][r] + sc[i][2][r] + sc[i][3][r];
#pragma unroll
                for (int off = 8; off >= 1; off >>= 1)
                    sum += __shfl_xor(sum, off);
                lrun[i][r] = lrun[i][r] * alpha[i][r] + sum;
            }
#pragma unroll
        for (int i = 0; i < 2; ++i)
#pragma unroll
            for (int n = 0; n < 4; ++n)
#pragma unroll
                for (int r = 0; r < 4; ++r)
                    oacc[i][n][r] *= alpha[i][r];

        // ---- P: C-layout regs -> LDS (bf16) ----
#pragma unroll
        for (int i = 0; i < 2; ++i)
#pragma unroll
            for (int s = 0; s < 4; ++s)
#pragma unroll
                for (int r = 0; r < 4; ++r)
                    Pl[wave][16 * i + quad * 4 + r][16 * s + r16] = (__bf16)sc[i][s][r];
        __builtin_amdgcn_s_waitcnt(0);   // wave-internal LDS ordering

        // ---- PV: A-frags of P from LDS, B-frags of V^T from global ----
        v8bf ap[2][2];
#pragma unroll
        for (int i = 0; i < 2; ++i)
#pragma unroll
            for (int kk = 0; kk < 2; ++kk)
                ap[i][kk] = *(const v8bf*)&Pl[wave][16 * i + r16][kk * 32 + quad * 8];
        v8bf bv[2][4];
#pragma unroll
        for (int kk = 0; kk < 2; ++kk)
#pragma unroll
            for (int n = 0; n < 4; ++n)
                bv[kk][n] = *(const v8bf*)(Vt + (size_t)(16 * n + r16) * SEQ
                                             + k0 + kk * 32 + quad * 8);
#pragma unroll
        for (int kk = 0; kk < 2; ++kk)
#pragma unroll
            for (int i = 0; i < 2; ++i)
#pragma unroll
                for (int n = 0; n < 4; ++n)
                    oacc[i][n] = __builtin_amdgcn_mfma_f32_16x16x32_bf16(
                        ap[i][kk], bv[kk][n], oacc[i][n], 0, 0, 0);
    }

    // ---- epilogue: O / l, scatter to [B,T,D] bf16 ----
    const int b = bh / NH, h = bh - b * NH;
#pragma unroll
    for (int i = 0; i < 2; ++i)
#pragma unroll
        for (int r = 0; r < 4; ++r) {
            const float inv = 1.0f / lrun[i][r];
            const int t = q0 + 16 * i + quad * 4 + r;
#pragma unroll
            for (int n = 0; n < 4; ++n) {
                const int d = 16 * n + r16;
                attnb[((size_t)(b * SEQ + t)) * DMODEL + h * DHEAD + d] =
                    (__bf16)(oacc[i][n][r] * inv);
            }
        }
}

// ---------------------------------------------------------------------------
// Kernel 3: out = attn @ Wproj^T + bproj (M=8192, N=768, K=768), fp32 out.
// ---------------------------------------------------------------------------
__global__ __launch_bounds__(256) void proj_kernel(
        const __bf16* __restrict__ A, const float* __restrict__ Wp,
        const float* __restrict__ bias, float* __restrict__ out) {
    const int lane = threadIdx.x & 63;
    const int wave = threadIdx.x >> 6;
    const int nb = blockIdx.x % 6;    // 768/128
    const int mb = blockIdx.x / 6;    // 8192/64
    const int waveM = mb * 64 + (wave >> 1) * 32;
    const int waveN = nb * 128 + (wave & 1) * 64;
    const int r16 = lane & 15;
    const int quad = lane >> 4;

    v4f acc[2][4] = {};
    for (int k0 = 0; k0 < DMODEL; k0 += 32) {
        const int kq = k0 + quad * 8;
        v8bf af[2], bfr[4];
#pragma unroll
        for (int i = 0; i < 2; ++i)
            af[i] = *(const v8bf*)(A + (size_t)(waveM + i * 16 + r16) * DMODEL + kq);
#pragma unroll
        for (int j = 0; j < 4; ++j)
            bfr[j] = cvt8(Wp + (size_t)(waveN + j * 16 + r16) * DMODEL + kq);
#pragma unroll
        for (int i = 0; i < 2; ++i)
#pragma unroll
            for (int j = 0; j < 4; ++j)
                acc[i][j] = __builtin_amdgcn_mfma_f32_16x16x32_bf16(
                    af[i], bfr[j], acc[i][j], 0, 0, 0);
    }

#pragma unroll
    for (int j = 0; j < 4; ++j) {
        const int n = waveN + j * 16 + r16;
        const float bv = bias[n];
#pragma unroll
        for (int i = 0; i < 2; ++i) {
#pragma unroll
            for (int r = 0; r < 4; ++r) {
                const int m = waveM + i * 16 + quad * 4 + r;
                out[(size_t)m * DMODEL + n] = acc[i][j][r] + bv;
            }
        }
    }
}

// ---------------------------------------------------------------------------
extern "C" void kernel_launch(void* const* d_in, const int* in_sizes, int n_in,
                              void* d_out, int out_size, void* d_ws, size_t ws_size,
                              hipStream_t stream) {
    const float* x     = (const float*)d_in[0];
    const float* Wqkv  = (const float*)d_in[1];
    const float* Wproj = (const float*)d_in[2];
    const float* bproj = (const float*)d_in[3];
    float* out = (float*)d_out;

    char* ws = (char*)d_ws;
    const size_t tsz = (size_t)BATCH * NH * SEQ * DHEAD * sizeof(__bf16); // 12.58 MB
    __bf16* Qb    = (__bf16*)(ws);
    __bf16* Kb    = (__bf16*)(ws + tsz);
    __bf16* Vtb   = (__bf16*)(ws + 2 * tsz);   // [B,H,DH,T] transposed
    __bf16* attnb = (__bf16*)(ws + 3 * tsz);   // [B,T,D]

    qkv_kernel<<<dim3(128 * 18), dim3(256), 0, stream>>>(x, Wqkv, Qb, Kb, Vtb);
    attn_kernel<<<dim3(16 * BATCH * NH), dim3(256), 0, stream>>>(Qb, Kb, Vtb, attnb);
    proj_kernel<<<dim3(128 * 6), dim3(256), 0, stream>>>(attnb, Wproj, bproj, out);
}

// Round 3
// 283.384 us; speedup vs baseline: 9.4434x; 2.1021x over previous
//
#include <hip/hip_runtime.h>
#include <hip/hip_bf16.h>

// B=4, T=2048, D=768, H=12, DH=64, causal MHA + QKV/out projections.
// All inputs fp32; internals bf16 (threshold 8*bf16eps permits this).
//
// R3: m97-style GEMMs. fp32->bf16 convert pass, then 128x128x32 LDS-staged
// MFMA GEMMs using global_load_lds width=16 (the 517->874 TF step on the
// measured ladder). Attention kernel unchanged from R2.

#define BATCH  4
#define SEQ    2048
#define DMODEL 768
#define NH     12
#define DHEAD  64
static constexpr float SCALE_LOG2E = 0.125f * 1.4426950408889634f;

#define N_X  (8192 * 768)   // x elements
#define N_WQ (2304 * 768)   // Wqkv elements
#define N_WP (768 * 768)    // Wproj elements

typedef __bf16 v8bf __attribute__((ext_vector_type(8)));
typedef float  v4f  __attribute__((ext_vector_type(4)));

__device__ __forceinline__ v8bf cvt8(const float* __restrict__ p) {
    const float4 a = ((const float4*)p)[0];
    const float4 b = ((const float4*)p)[1];
    v8bf r;
    r[0] = (__bf16)a.x; r[1] = (__bf16)a.y; r[2] = (__bf16)a.z; r[3] = (__bf16)a.w;
    r[4] = (__bf16)b.x; r[5] = (__bf16)b.y; r[6] = (__bf16)b.z; r[7] = (__bf16)b.w;
    return r;
}

// async global->LDS, 16 bytes: HW writes lane i at (wave-uniform lds)+i*16.
__device__ __forceinline__ void async_copy16(__bf16* lds, const __bf16* g) {
    __builtin_amdgcn_global_load_lds(
        (const __attribute__((address_space(1))) void*)g,
        (__attribute__((address_space(3))) void*)lds, 16, 0, 0);
}

// ---------------------------------------------------------------------------
// Kernel 0: fp32 -> bf16 convert of x, Wqkv, Wproj (one fused pass).
// ---------------------------------------------------------------------------
__global__ __launch_bounds__(256) void cvt_kernel(
        const float* __restrict__ x, const float* __restrict__ Wq,
        const float* __restrict__ Wp, __bf16* __restrict__ xb,
        __bf16* __restrict__ Wqb, __bf16* __restrict__ Wpb) {
    const long e = ((long)blockIdx.x * 256 + threadIdx.x) * 8;
    const float* src;
    __bf16* dst;
    if (e < N_X)             { src = x  + e;               dst = xb  + e; }
    else if (e < N_X + N_WQ) { src = Wq + (e - N_X);        dst = Wqb + (e - N_X); }
    else                     { src = Wp + (e - N_X - N_WQ); dst = Wpb + (e - N_X - N_WQ); }
    *(v8bf*)dst = cvt8(src);
}

// ---------------------------------------------------------------------------
// Kernel 1: qkv = xb @ Wqkvb^T (M=8192, N=2304, K=768), m97 structure.
// Block 256 thr / 4 waves, tile 128x128, BK=32, global_load_lds staging.
// Epilogue scatters: Q [B,H,T,64] (pre-scaled), K [B,H,T,64], V^T [B,H,64,T].
// ---------------------------------------------------------------------------
__global__ __launch_bounds__(256) void qkv_gemm(
        const __bf16* __restrict__ xb, const __bf16* __restrict__ Wb,
        __bf16* __restrict__ Qb, __bf16* __restrict__ Kb, __bf16* __restrict__ Vtb) {
    __shared__ __bf16 As[128 * 32], Bs[128 * 32];   // 8 KB each
    const int lane = threadIdx.x & 63, wave = threadIdx.x >> 6;
    const int nb = blockIdx.x % 18, mb = blockIdx.x / 18;
    const int r16 = lane & 15, quad = lane >> 4;
    const int wm = (wave >> 1) * 64, wn = (wave & 1) * 64;
    const __bf16* Asrc = xb + (size_t)mb * 128 * DMODEL;
    const __bf16* Bsrc = Wb + (size_t)nb * 128 * DMODEL;

    v4f acc[4][4] = {};
    for (int k0 = 0; k0 < DMODEL; k0 += 32) {
#pragma unroll
        for (int p = 0; p < 2; ++p) {
            const int cb = p * 256 + wave * 64;      // wave-uniform chunk base
            const int c = cb + lane;
            const int row = c >> 2, sg = c & 3;
            async_copy16(&As[cb * 8], Asrc + (size_t)row * DMODEL + k0 + sg * 8);
            async_copy16(&Bs[cb * 8], Bsrc + (size_t)row * DMODEL + k0 + sg * 8);
        }
        __syncthreads();                             // drains vmcnt before barrier
        v8bf a[4], b[4];
#pragma unroll
        for (int i = 0; i < 4; ++i)
            a[i] = *(const v8bf*)&As[(wm + 16 * i + r16) * 32 + quad * 8];
#pragma unroll
        for (int j = 0; j < 4; ++j)
            b[j] = *(const v8bf*)&Bs[(wn + 16 * j + r16) * 32 + quad * 8];
#pragma unroll
        for (int i = 0; i < 4; ++i)
#pragma unroll
            for (int j = 0; j < 4; ++j)
                acc[i][j] = __builtin_amdgcn_mfma_f32_16x16x32_bf16(
                    a[i], b[j], acc[i][j], 0, 0, 0);
        __syncthreads();                             // WAR before next stage
    }

    // epilogue: whole block is within one of Q/K/V (128 | 768)
    const int seg = nb / 6;                          // 0=Q 1=K 2=V
    const int nl0 = (nb % 6) * 128 + wn;
#pragma unroll
    for (int j = 0; j < 4; ++j) {
        const int n = nl0 + 16 * j + r16;            // 0..767 within segment
        const int h = n >> 6, d = n & 63;
#pragma unroll
        for (int i = 0; i < 4; ++i) {
            const int mrow = mb * 128 + wm + 16 * i + quad * 4;
#pragma unroll
            for (int r = 0; r < 4; ++r) {
                const int m = mrow + r;
                const int bidx = m >> 11, t = m & (SEQ - 1);
                const size_t base = ((size_t)(bidx * NH + h)) * SEQ * DHEAD;
                if (seg == 0)
                    Qb[base + (size_t)t * DHEAD + d] = (__bf16)(acc[i][j][r] * SCALE_LOG2E);
                else if (seg == 1)
                    Kb[base + (size_t)t * DHEAD + d] = (__bf16)acc[i][j][r];
                else
                    Vtb[base + (size_t)d * SEQ + t] = (__bf16)acc[i][j][r];
            }
        }
    }
}

// ---------------------------------------------------------------------------
// Kernel 2: MFMA causal flash attention (unchanged from R2).
// ---------------------------------------------------------------------------
__global__ __launch_bounds__(256) void attn_kernel(
        const __bf16* __restrict__ Qb, const __bf16* __restrict__ Kb,
        const __bf16* __restrict__ Vtb, __bf16* __restrict__ attnb) {
    __shared__ __align__(16) __bf16 Pl[4][32][72];
    const int lane = threadIdx.x & 63;
    const int wave = threadIdx.x >> 6;
    const int bh = blockIdx.x % (BATCH * NH);
    const int qt = 15 - (blockIdx.x / (BATCH * NH));  // longest blocks first
    const int q0 = qt * 128 + wave * 32;
    const int r16 = lane & 15;
    const int quad = lane >> 4;

    const __bf16* Q  = Qb  + (size_t)bh * SEQ * DHEAD;
    const __bf16* K  = Kb  + (size_t)bh * SEQ * DHEAD;
    const __bf16* Vt = Vtb + (size_t)bh * DHEAD * SEQ;

    v8bf aq[2][2];
#pragma unroll
    for (int i = 0; i < 2; ++i)
#pragma unroll
        for (int kk = 0; kk < 2; ++kk)
            aq[i][kk] = *(const v8bf*)(Q + (size_t)(q0 + 16 * i + r16) * DHEAD
                                         + kk * 32 + quad * 8);

    v4f  oacc[2][4] = {};
    float mrun[2][4], lrun[2][4];
#pragma unroll
    for (int i = 0; i < 2; ++i)
#pragma unroll
        for (int r = 0; r < 4; ++r) { mrun[i][r] = -1e30f; lrun[i][r] = 0.f; }

    const int tmax = q0 + 31;
    for (int k0 = 0; k0 <= tmax; k0 += 64) {
        v8bf bk[4][2];
#pragma unroll
        for (int s = 0; s < 4; ++s)
#pragma unroll
            for (int kk = 0; kk < 2; ++kk)
                bk[s][kk] = *(const v8bf*)(K + (size_t)(k0 + 16 * s + r16) * DHEAD
                                             + kk * 32 + quad * 8);
        v4f sc[2][4] = {};
#pragma unroll
        for (int kk = 0; kk < 2; ++kk)
#pragma unroll
            for (int i = 0; i < 2; ++i)
#pragma unroll
                for (int s = 0; s < 4; ++s)
                    sc[i][s] = __builtin_amdgcn_mfma_f32_16x16x32_bf16(
                        aq[i][kk], bk[s][kk], sc[i][s], 0, 0, 0);

        if (k0 + 63 > q0) {
#pragma unroll
            for (int i = 0; i < 2; ++i)
#pragma unroll
                for (int s = 0; s < 4; ++s)
#pragma unroll
                    for (int r = 0; r < 4; ++r) {
                        const int row = q0 + 16 * i + quad * 4 + r;
                        const int col = k0 + 16 * s + r16;
                        if (col > row) sc[i][s][r] = -1e30f;
                    }
        }

        float rmax[2][4];
#pragma unroll
        for (int i = 0; i < 2; ++i)
#pragma unroll
            for (int r = 0; r < 4; ++r) {
                float m = fmaxf(fmaxf(sc[i][0][r], sc[i][1][r]),
                                fmaxf(sc[i][2][r], sc[i][3][r]));
#pragma unroll
                for (int off = 8; off >= 1; off >>= 1)
                    m = fmaxf(m, __shfl_xor(m, off));
                rmax[i][r] = m;
            }
        float alpha[2][4];
#pragma unroll
        for (int i = 0; i < 2; ++i)
#pragma unroll
            for (int r = 0; r < 4; ++r) {
                const float mnew = fmaxf(mrun[i][r], rmax[i][r]);
                alpha[i][r] = __builtin_exp2f(mrun[i][r] - mnew);
                mrun[i][r] = mnew;
            }
#pragma unroll
        for (int i = 0; i < 2; ++i)
#pragma unroll
            for (int s = 0; s < 4; ++s)
#pragma unroll
                for (int r = 0; r < 4; ++r)
                    sc[i][s][r] = __builtin_exp2f(sc[i][s][r] - mrun[i][r]);
#pragma unroll
        for (int i = 0; i < 2; ++i)
#pragma unroll
            for (int r = 0; r < 4; ++r) {
                float sum = sc[i][0][r] + sc[i][1][r] + sc[i][2][r] + sc[i][3][r];
#pragma unroll
                for (int off = 8; off >= 1; off >>= 1)
                    sum += __shfl_xor(sum, off);
                lrun[i][r] = lrun[i][r] * alpha[i][r] + sum;
            }
#pragma unroll
        for (int i = 0; i < 2; ++i)
#pragma unroll
            for (int n = 0; n < 4; ++n)
#pragma unroll
                for (int r = 0; r < 4; ++r)
                    oacc[i][n][r] *= alpha[i][r];

#pragma unroll
        for (int i = 0; i < 2; ++i)
#pragma unroll
            for (int s = 0; s < 4; ++s)
#pragma unroll
                for (int r = 0; r < 4; ++r)
                    Pl[wave][16 * i + quad * 4 + r][16 * s + r16] = (__bf16)sc[i][s][r];
        __builtin_amdgcn_s_waitcnt(0);

        v8bf ap[2][2];
#pragma unroll
        for (int i = 0; i < 2; ++i)
#pragma unroll
            for (int kk = 0; kk < 2; ++kk)
                ap[i][kk] = *(const v8bf*)&Pl[wave][16 * i + r16][kk * 32 + quad * 8];
        v8bf bv[2][4];
#pragma unroll
        for (int kk = 0; kk < 2; ++kk)
#pragma unroll
            for (int n = 0; n < 4; ++n)
                bv[kk][n] = *(const v8bf*)(Vt + (size_t)(16 * n + r16) * SEQ
                                             + k0 + kk * 32 + quad * 8);
#pragma unroll
        for (int kk = 0; kk < 2; ++kk)
#pragma unroll
            for (int i = 0; i < 2; ++i)
#pragma unroll
                for (int n = 0; n < 4; ++n)
                    oacc[i][n] = __builtin_amdgcn_mfma_f32_16x16x32_bf16(
                        ap[i][kk], bv[kk][n], oacc[i][n], 0, 0, 0);
    }

    const int b = bh / NH, h = bh - b * NH;
#pragma unroll
    for (int i = 0; i < 2; ++i)
#pragma unroll
        for (int r = 0; r < 4; ++r) {
            const float inv = 1.0f / lrun[i][r];
            const int t = q0 + 16 * i + quad * 4 + r;
#pragma unroll
            for (int n = 0; n < 4; ++n) {
                const int d = 16 * n + r16;
                attnb[((size_t)(b * SEQ + t)) * DMODEL + h * DHEAD + d] =
                    (__bf16)(oacc[i][n][r] * inv);
            }
        }
}

// ---------------------------------------------------------------------------
// Kernel 3: out = attnb @ Wprojb^T + bproj (M=8192, N=768, K=768), m97
// structure, fp32 out.
// ---------------------------------------------------------------------------
__global__ __launch_bounds__(256) void proj_gemm(
        const __bf16* __restrict__ Ab, const __bf16* __restrict__ Wb,
        const float* __restrict__ bias, float* __restrict__ out) {
    __shared__ __bf16 As[128 * 32], Bs[128 * 32];
    const int lane = threadIdx.x & 63, wave = threadIdx.x >> 6;
    const int nb = blockIdx.x % 6, mb = blockIdx.x / 6;
    const int r16 = lane & 15, quad = lane >> 4;
    const int wm = (wave >> 1) * 64, wn = (wave & 1) * 64;
    const __bf16* Asrc = Ab + (size_t)mb * 128 * DMODEL;
    const __bf16* Bsrc = Wb + (size_t)nb * 128 * DMODEL;

    v4f acc[4][4] = {};
    for (int k0 = 0; k0 < DMODEL; k0 += 32) {
#pragma unroll
        for (int p = 0; p < 2; ++p) {
            const int cb = p * 256 + wave * 64;
            const int c = cb + lane;
            const int row = c >> 2, sg = c & 3;
            async_copy16(&As[cb * 8], Asrc + (size_t)row * DMODEL + k0 + sg * 8);
            async_copy16(&Bs[cb * 8], Bsrc + (size_t)row * DMODEL + k0 + sg * 8);
        }
        __syncthreads();
        v8bf a[4], b[4];
#pragma unroll
        for (int i = 0; i < 4; ++i)
            a[i] = *(const v8bf*)&As[(wm + 16 * i + r16) * 32 + quad * 8];
#pragma unroll
        for (int j = 0; j < 4; ++j)
            b[j] = *(const v8bf*)&Bs[(wn + 16 * j + r16) * 32 + quad * 8];
#pragma unroll
        for (int i = 0; i < 4; ++i)
#pragma unroll
            for (int j = 0; j < 4; ++j)
                acc[i][j] = __builtin_amdgcn_mfma_f32_16x16x32_bf16(
                    a[i], b[j], acc[i][j], 0, 0, 0);
        __syncthreads();
    }

#pragma unroll
    for (int j = 0; j < 4; ++j) {
        const int n = nb * 128 + wn + 16 * j + r16;
        const float bv = bias[n];
#pragma unroll
        for (int i = 0; i < 4; ++i) {
            const int mrow = mb * 128 + wm + 16 * i + quad * 4;
#pragma unroll
            for (int r = 0; r < 4; ++r)
                out[(size_t)(mrow + r) * DMODEL + n] = acc[i][j][r] + bv;
        }
    }
}

// ---------------------------------------------------------------------------
extern "C" void kernel_launch(void* const* d_in, const int* in_sizes, int n_in,
                              void* d_out, int out_size, void* d_ws, size_t ws_size,
                              hipStream_t stream) {
    const float* x     = (const float*)d_in[0];
    const float* Wqkv  = (const float*)d_in[1];
    const float* Wproj = (const float*)d_in[2];
    const float* bproj = (const float*)d_in[3];
    float* out = (float*)d_out;

    char* ws = (char*)d_ws;
    const size_t tsz = (size_t)BATCH * NH * SEQ * DHEAD * sizeof(__bf16); // 12.58 MB
    __bf16* Qb    = (__bf16*)(ws);
    __bf16* Kb    = (__bf16*)(ws + tsz);
    __bf16* Vtb   = (__bf16*)(ws + 2 * tsz);          // [B,H,DH,T]
    __bf16* xb    = (__bf16*)(ws + 3 * tsz);          // aliased with attnb:
    __bf16* attnb = (__bf16*)(ws + 3 * tsz);          // xb dead before attn writes
    __bf16* Wqb   = (__bf16*)(ws + 4 * tsz);
    __bf16* Wpb   = (__bf16*)(ws + 4 * tsz + (size_t)N_WQ * 2);

    cvt_kernel<<<dim3((N_X + N_WQ + N_WP) / (8 * 256)), dim3(256), 0, stream>>>(
        x, Wqkv, Wproj, xb, Wqb, Wpb);
    qkv_gemm<<<dim3(64 * 18), dim3(256), 0, stream>>>(xb, Wqb, Qb, Kb, Vtb);
    attn_kernel<<<dim3(16 * BATCH * NH), dim3(256), 0, stream>>>(Qb, Kb, Vtb, attnb);
    proj_gemm<<<dim3(64 * 6), dim3(256), 0, stream>>>(attnb, Wpb, bproj, out);
}